// Round 12
// baseline (24536.278 us; speedup 1.0000x reference)
//
#include <hip/hip_runtime.h>

namespace {
constexpr int TT   = 2048;
constexpr int NBLK = 128;
constexpr size_t YSZ = (size_t)32 * TT * 512;
constexpr size_t HFO = YSZ;
constexpr size_t CFO = YSZ + (size_t)2 * 32 * 512;
// LDS map (151680 B total, fully disjoint)
constexpr int O_WLO = 32768;
constexpr int O_AST = 65536;            // 64 KB: wave0 hi rows [b*1024], wave1 lo at +32768
constexpr int O_B0  = 131072;           // 8 KB chunk buf 0
constexpr int O_B1  = 139264;           // 8 KB chunk buf 1
constexpr int O_GA  = 147456;           // 2112 B
constexpr int O_XGB = 149568;           // 2112 B
}

typedef float f32x4 __attribute__((ext_vector_type(4)));
typedef short s16x8 __attribute__((ext_vector_type(8)));

__device__ __forceinline__ float sigf(float v)  { return 1.0f / (1.0f + __expf(-v)); }
__device__ __forceinline__ float tanh_(float v) { return 1.0f - 2.0f / (__expf(2.0f * v) + 1.0f); }
__device__ __forceinline__ short f2bf(float v) {
  unsigned u = __float_as_uint(v);
  u += 0x7FFFu + ((u >> 16) & 1u);
  return (short)(u >> 16);
}
__device__ __forceinline__ float bf2f(short h) {
  return __uint_as_float(((unsigned)(unsigned short)h) << 16);
}
__device__ __forceinline__ void st_short_coh(void* p, int v) {
  asm volatile("global_store_short %0, %1, off sc1" :: "v"(p), "v"(v) : "memory");
}
__device__ __forceinline__ void st_flag(int* p, int v) {
  __hip_atomic_store(p, v, __ATOMIC_RELAXED, __HIP_MEMORY_SCOPE_AGENT);
}
__device__ __forceinline__ void poll_ge(const int* f, int need) {
  while (__hip_atomic_load(f, __ATOMIC_RELAXED, __HIP_MEMORY_SCOPE_AGENT) < need)
    __builtin_amdgcn_s_sleep(1);
}
__device__ __forceinline__ void cvt8(const f32x4& p, const f32x4& q, s16x8& bh, s16x8& bl) {
  const float pv[8] = {p.x, p.y, p.z, p.w, q.x, q.y, q.z, q.w};
#pragma unroll
  for (int j = 0; j < 8; ++j) {
    const short h = f2bf(pv[j]);
    bh[j] = h;
    bl[j] = f2bf(pv[j] - bf2f(h));
  }
}

#define GLLP(g, l) __builtin_amdgcn_global_load_lds(                          \
    (const __attribute__((address_space(1))) void*)(g),                       \
    (__attribute__((address_space(3))) void*)(l), 16, 0, 0)
#define GLLC(g, l) __builtin_amdgcn_global_load_lds(                          \
    (const __attribute__((address_space(1))) void*)(g),                       \
    (__attribute__((address_space(3))) void*)(l), 16, 0, 0x11)

#define VMCNT4() do { asm volatile("s_waitcnt vmcnt(4)" ::: "memory"); __builtin_amdgcn_sched_barrier(0); } while (0)
#define VMCNT0() do { asm volatile("s_waitcnt vmcnt(0)" ::: "memory"); __builtin_amdgcn_sched_barrier(0); } while (0)
#define LGKM0()  do { asm volatile("s_waitcnt lgkmcnt(0)" ::: "memory"); __builtin_amdgcn_sched_barrier(0); } while (0)
#define BAR()    do { __builtin_amdgcn_s_barrier(); __builtin_amdgcn_sched_barrier(0); } while (0)

__global__ __launch_bounds__(256)
void lstm_persist(
    const float* __restrict__ x,
    const float* __restrict__ Wih0, const float* __restrict__ Whh0,
    const float* __restrict__ bih0, const float* __restrict__ bhh0,
    const float* __restrict__ Wih1, const float* __restrict__ Whh1,
    const float* __restrict__ bih1, const float* __restrict__ bhh1,
    const float* __restrict__ h0c, const float* __restrict__ c0c,
    float* __restrict__ out,
    short* __restrict__ r0hi, short* __restrict__ r0lo,
    short* __restrict__ r1hi, short* __restrict__ r1lo,
    int* __restrict__ flags0, int* __restrict__ flags1)
{
  __shared__ __align__(16) char LDS[151680];
  char* Whi = LDS;                       // 16 rows x 2048 B, src-swizzled (k<<1)^((row&15)<<4)
  char* Wlo = LDS + O_WLO;
  char* Ast = LDS + O_AST;
  char* const Bst0 = LDS + O_B0;
  char* const Bst1 = LDS + O_B1;
  float* gA  = (float*)(LDS + O_GA);
  float* xgb = (float*)(LDS + O_XGB);

  const int tid   = (int)threadIdx.x;
  const int lane  = tid & 63;
  const int w     = tid >> 6;            // 0,1 = A-waves (recurrent half); 2,3 = B-waves (ff half + cell)
  const int layer = (int)(blockIdx.x >> 7);
  const int lb    = (int)(blockIdx.x & (NBLK - 1));
  const int j0    = lb << 2;
  const bool isA  = (w < 2);

  const float* Wih = layer ? Wih1 : Wih0;
  const float* Whh = layer ? Whh1 : Whh0;
  const float* bih = layer ? bih1 : bih0;
  const float* bhh = layer ? bhh1 : bhh0;
  short* rhiO = layer ? r1hi : r0hi;     // own-layer h ring (producer + A-consumer)
  short* rloO = layer ? r1lo : r0lo;
  int* flO = layer ? flags1 : flags0;    // 256 flags/layer (2 per block)

  // ---- prologue: W -> bf16 hi/lo planes (src-swizzled), bias/c0 ----
  for (int idx = tid; idx < 16 * 1024; idx += 256) {
    const int row = idx >> 10;           // gate*4 + jj
    const int k   = idx & 1023;          // 0-511 Wih cols, 512-1023 Whh cols
    const int rg  = ((row >> 2) << 9) + j0 + (row & 3);
    const float v = (k < 512) ? Wih[(rg << 9) + k] : Whh[(rg << 9) + (k - 512)];
    const short h = f2bf(v);
    const short l = f2bf(v - bf2f(h));
    const int byte = (row << 11) + ((k << 1) ^ ((row & 15) << 4));
    *(short*)(Whi + byte) = h;
    *(short*)(Wlo + byte) = l;
  }
  float creg = 0.0f;
  float bias_[4] = {0.f, 0.f, 0.f, 0.f};
  int jjC = 0, bC = 0;
  if (!isA) {
    jjC = lane >> 4;
    bC  = ((w - 2) << 4) + (lane & 15);
    creg = c0c[layer * 512 + j0 + jjC];
#pragma unroll
    for (int g = 0; g < 4; ++g) {
      const int rg = (g << 9) + j0 + jjC;
      bias_[g] = bih[rg] + bhh[rg];
    }
  }

  // MFMA lane constants (A-frag row = lane&15, k-group = lane>>4; C: row=kg*4+r, col=lane&15)
  const int arow = lane & 15;
  const int kg   = lane >> 4;
  const int wsz  = arow << 4;
  const int bbA  = (w << 4) + (lane & 15);        // A-wave batch row
  const int uszA = (bbA & 15) << 4;
  const int bbB  = ((w - 2) << 4) + (lane & 15);  // B-wave batch row
  const int uszB  = (bbB & 15) << 4;              // layer-0 chunk swizzle (256-B rows)
  const int uszB7 = (bbB & 7) << 4;               // layer-1 chunk swizzle (128-B rows)

  // ---- prologue: stage A(0) = fp32 broadcast of h init (cvt path at s==0) ----
  if (isA) {
    const char* src0 = (const char*)(h0c + layer * 512);
#pragma unroll 1
    for (int i = 0; i < 32; ++i) {
      const int g = (w << 5) + i;        // 64 GLLs of 1 KB -> [b][2048 B]
      const int b = g >> 1, half = g & 1;
      GLLP(src0 + (half << 10) + ((lane << 4) ^ ((b & 15) << 4)),
           Ast + (b << 11) + (half << 10));
    }
    VMCNT0();
  }
  BAR();

#pragma unroll 1
  for (int s = 0; s < TT; ++s) {
    const int slot = s & 3;
    if (isA) {
      // ======== A: recurrent-half MFMA (W cols 512..1023 x staged h) ========
      f32x4 a0 = {0.f,0.f,0.f,0.f}, a1 = {0.f,0.f,0.f,0.f};
#pragma unroll
      for (int ks = 0; ks < 16; ++ks) {
        const int wk = 512 + (ks << 5) + (kg << 3);
        const int wb = ((wk << 1) ^ wsz);
        const s16x8 ah = *(const s16x8*)(Whi + (arow << 11) + wb);
        const s16x8 al = *(const s16x8*)(Wlo + (arow << 11) + wb);
        const int uk = (ks << 5) + (kg << 3);
        s16x8 bh, bl;
        if (s == 0) {
          const f32x4 p = *(const f32x4*)(Ast + (bbA << 11) + ((uk << 2) ^ uszA));
          const f32x4 q = *(const f32x4*)(Ast + (bbA << 11) + (((uk + 4) << 2) ^ uszA));
          cvt8(p, q, bh, bl);
        } else {
          const int ub = (uk << 1) ^ uszA;
          bh = *(const s16x8*)(Ast + (bbA << 10) + ub);
          bl = *(const s16x8*)(Ast + 32768 + (bbA << 10) + ub);
        }
        if (ks & 1) {
          a1 = __builtin_amdgcn_mfma_f32_16x16x32_bf16(ah, bh, a1, 0, 0, 0);
          a1 = __builtin_amdgcn_mfma_f32_16x16x32_bf16(ah, bl, a1, 0, 0, 0);
          a1 = __builtin_amdgcn_mfma_f32_16x16x32_bf16(al, bh, a1, 0, 0, 0);
        } else {
          a0 = __builtin_amdgcn_mfma_f32_16x16x32_bf16(ah, bh, a0, 0, 0, 0);
          a0 = __builtin_amdgcn_mfma_f32_16x16x32_bf16(ah, bl, a0, 0, 0, 0);
          a0 = __builtin_amdgcn_mfma_f32_16x16x32_bf16(al, bh, a0, 0, 0, 0);
        }
      }
      const f32x4 c = a0 + a1;
#pragma unroll
      for (int r = 0; r < 4; ++r) gA[((kg << 2) + r) * 33 + bbA] = c[r];
      LGKM0();
      BAR();                             // mid: gA visible; Ast reads of step s done
      if (s + 1 < TT) {
        poll_ge(flO + tid, s + 1);       // all blocks' h[s] complete (2 flags/block)
        poll_ge(flO + 128 + tid, s + 1);
        if (layer == 0 && s >= 3) {      // L1 consumed y0[s-3] -> slot reusable at s+1
          poll_ge(flags1 + tid, s - 2);
          poll_ge(flags1 + 128 + tid, s - 2);
        }
        // stage A(s+1) = h[s] planes: wave0 hi, wave1 lo
        const char* sp = (const char*)(w == 0 ? rhiO : rloO);
#pragma unroll 1
        for (int b = 0; b < 32; ++b) {
          GLLC(sp + ((((slot << 5) + b) << 10)) + ((lane << 4) ^ ((b & 15) << 4)),
               Ast + (w << 15) + (b << 10));
        }
        VMCNT0();
      }
      BAR();                             // end
    } else {
      // ======== B: feedforward-half MFMA (W cols 0..511), 8 chunks K=64 ========
      if (layer == 1) {                  // y0[s] ready (L0 leads)
        poll_ge(flags0 + (tid - 128), s + 1);
        poll_ge(flags0 + (tid - 128) + 128, s + 1);
      }
      const int bw = w - 2;
      auto issueChunk = [&](char* buf, int c) {
        if (layer == 0) {                // x[.,s,c*64..]: 16 rows x 256 B per wave = 4 GLLs
#pragma unroll
          for (int j = 0; j < 4; ++j) {
            const int b = (bw << 4) + (j << 2) + (lane >> 4);
            const char* src = (const char*)x
                + ((((size_t)b * 2048 + s) * 512 + ((size_t)c << 6)) << 2)
                + (((lane & 15) << 4) ^ ((b & 15) << 4));
            GLLP(src, buf + (((bw << 4) + (j << 2)) << 8));
          }
        } else {                         // y0[s] planes: 16 rows x 128 B, hi+lo = 4 GLLs
#pragma unroll
          for (int j = 0; j < 4; ++j) {
            const int hi = (j < 2);
            const int b = (bw << 4) + ((j & 1) << 3) + (lane >> 3);
            const char* rb = hi ? (const char*)r0hi : (const char*)r0lo;
            const char* src = rb
                + (((((size_t)slot << 5) + b) * 512 + ((size_t)c << 6)) << 1)
                + (((lane & 7) << 4) ^ ((b & 7) << 4));
            GLLC(src, buf + (hi ? 0 : 4096) + (((bw << 4) + ((j & 1) << 3)) << 7));
          }
        }
      };
      auto mfmaChunk = [&](const char* buf, int c, f32x4& a0, f32x4& a1) {
#pragma unroll
        for (int i = 0; i < 2; ++i) {
          const int wk = (c << 6) + (i << 5) + (kg << 3);
          const int wb = ((wk << 1) ^ wsz);
          const s16x8 ah = *(const s16x8*)(Whi + (arow << 11) + wb);
          const s16x8 al = *(const s16x8*)(Wlo + (arow << 11) + wb);
          const int kk = (i << 5) + (kg << 3);
          s16x8 bh, bl;
          if (layer == 0) {
            const f32x4 p = *(const f32x4*)(buf + (bbB << 8) + ((kk << 2) ^ uszB));
            const f32x4 q = *(const f32x4*)(buf + (bbB << 8) + (((kk + 4) << 2) ^ uszB));
            cvt8(p, q, bh, bl);
          } else {
            const int ub = (kk << 1) ^ uszB7;
            bh = *(const s16x8*)(buf + (bbB << 7) + ub);
            bl = *(const s16x8*)(buf + 4096 + (bbB << 7) + ub);
          }
          if (i & 1) {
            a1 = __builtin_amdgcn_mfma_f32_16x16x32_bf16(ah, bh, a1, 0, 0, 0);
            a1 = __builtin_amdgcn_mfma_f32_16x16x32_bf16(ah, bl, a1, 0, 0, 0);
            a1 = __builtin_amdgcn_mfma_f32_16x16x32_bf16(al, bh, a1, 0, 0, 0);
          } else {
            a0 = __builtin_amdgcn_mfma_f32_16x16x32_bf16(ah, bh, a0, 0, 0, 0);
            a0 = __builtin_amdgcn_mfma_f32_16x16x32_bf16(ah, bl, a0, 0, 0, 0);
            a0 = __builtin_amdgcn_mfma_f32_16x16x32_bf16(al, bh, a0, 0, 0, 0);
          }
        }
      };
      f32x4 a0 = {0.f,0.f,0.f,0.f}, a1 = {0.f,0.f,0.f,0.f};
      issueChunk(Bst0, 0);
      issueChunk(Bst1, 1);
#pragma unroll 1
      for (int c = 0; c < 8; ++c) {
        if (c == 7) { VMCNT0(); } else { VMCNT4(); }
        char* buf = (c & 1) ? Bst1 : Bst0;
        mfmaChunk(buf, c, a0, a1);
        __builtin_amdgcn_sched_barrier(0);        // pin: reads of buf before re-issue into it
        if (c < 6) issueChunk(buf, c + 2);
      }
      BAR();                             // mid: gA from A-waves now visible
      const f32x4 cf = a0 + a1;
#pragma unroll
      for (int r = 0; r < 4; ++r) xgb[((kg << 2) + r) * 33 + bbB] = cf[r];
      LGKM0();                           // intra-wave: xgb rows for own cols ready
      // ---- cell ----
      float gv[4];
#pragma unroll
      for (int g = 0; g < 4; ++g) {
        const int rowi = ((g << 2) + jjC) * 33 + bC;
        gv[g] = gA[rowi] + xgb[rowi] + bias_[g];
      }
      const float cn = sigf(gv[1]) * creg + sigf(gv[0]) * tanh_(gv[2]);
      const float hn = sigf(gv[3]) * tanh_(cn);
      creg = cn;
      const int j = j0 + jjC;
      const short hb = f2bf(hn);
      const short lo2 = f2bf(hn - bf2f(hb));
      st_short_coh(rhiO + (((slot << 5) + bC) << 9) + j, (int)hb);
      st_short_coh(rloO + (((slot << 5) + bC) << 9) + j, (int)lo2);
      if (layer == 1) out[(((size_t)bC * 2048 + s) << 9) + j] = hn;
      if (s == TT - 1) out[HFO + (size_t)(((layer << 5) + bC) << 9) + j] = hn;
      VMCNT0();                          // h planes at coherence point
      if (lane == 0) st_flag(flO + (lb << 1) + (w - 2), s + 1);
      BAR();                             // end
    }
  }

  if (!isA)
    out[CFO + (size_t)(((layer << 5) + bC) << 9) + j0 + jjC] = creg;
}

extern "C" void kernel_launch(void* const* d_in, const int* in_sizes, int n_in,
                              void* d_out, int out_size, void* d_ws, size_t ws_size,
                              hipStream_t stream) {
  (void)in_sizes; (void)n_in; (void)out_size; (void)ws_size;
  const float* x    = (const float*)d_in[0];
  const float* Wih0 = (const float*)d_in[1];
  const float* Whh0 = (const float*)d_in[2];
  const float* bih0 = (const float*)d_in[3];
  const float* bhh0 = (const float*)d_in[4];
  const float* Wih1 = (const float*)d_in[5];
  const float* Whh1 = (const float*)d_in[6];
  const float* bih1 = (const float*)d_in[7];
  const float* bhh1 = (const float*)d_in[8];
  const float* h0   = (const float*)d_in[9];
  const float* c0   = (const float*)d_in[10];

  float* out = (float*)d_out;
  short* r0hi = (short*)d_ws;                            // 4 slots x 32 x 512 x 2B = 128 KB each
  short* r0lo = (short*)((char*)d_ws + (128 << 10));
  short* r1hi = (short*)((char*)d_ws + (256 << 10));
  short* r1lo = (short*)((char*)d_ws + (384 << 10));
  int* flags0 = (int*)((char*)d_ws + (512 << 10));       // 256 ints
  int* flags1 = (int*)((char*)d_ws + (512 << 10) + 1024);

  hipMemsetAsync(flags0, 0, 2048, stream);

  hipLaunchKernelGGL(lstm_persist, dim3(2 * NBLK), dim3(256), 0, stream,
                     x, Wih0, Whh0, bih0, bhh0, Wih1, Whh1, bih1, bhh1,
                     h0, c0, out, r0hi, r0lo, r1hi, r1lo, flags0, flags1);
}

// Round 13
// 19905.951 us; speedup vs baseline: 1.2326x; 1.2326x over previous
//
#include <hip/hip_runtime.h>

namespace {
constexpr int TT    = 2048;
constexpr int NBLK  = 128;
constexpr int RING0 = 8;    // L0 h ring slots (feeds L1's B)
constexpr int RING1 = 4;    // L1 h ring slots
constexpr size_t YSZ = (size_t)32 * TT * 512;
constexpr size_t HFO = YSZ;
constexpr size_t CFO = YSZ + (size_t)2 * 32 * 512;
// LDS map (158048 B, disjoint)
constexpr int O_WLO = 32768;
constexpr int O_AST = 65536;   // 64 KB: hi plane 32 KB, lo at +32768 (fp32 64 KB at s==0)
constexpr int O_B0  = 131072;  // 8 KB chunk buf
constexpr int O_B1  = 139264;  // 8 KB chunk buf
constexpr int O_GB  = 147456;  // 2112 B gbuf (A-internal)
constexpr int O_XGB = 149568;  // 4 slots x 2112 B xg ring
constexpr int O_LF  = 158016;  // 8 LDS flags: as[2], am[2], xf[2], xc[2]
}

typedef float f32x4 __attribute__((ext_vector_type(4)));
typedef short s16x8 __attribute__((ext_vector_type(8)));

__device__ __forceinline__ float sigf(float v)  { return 1.0f / (1.0f + __expf(-v)); }
__device__ __forceinline__ float tanh_(float v) { return 1.0f - 2.0f / (__expf(2.0f * v) + 1.0f); }
__device__ __forceinline__ short f2bf(float v) {
  unsigned u = __float_as_uint(v);
  u += 0x7FFFu + ((u >> 16) & 1u);
  return (short)(u >> 16);
}
__device__ __forceinline__ float bf2f(short h) {
  return __uint_as_float(((unsigned)(unsigned short)h) << 16);
}
__device__ __forceinline__ void st_short_coh(void* p, int v) {
  asm volatile("global_store_short %0, %1, off sc1" :: "v"(p), "v"(v) : "memory");
}
__device__ __forceinline__ void st_flag(int* p, int v) {
  __hip_atomic_store(p, v, __ATOMIC_RELAXED, __HIP_MEMORY_SCOPE_AGENT);
}
__device__ __forceinline__ void poll_ge(const int* f, int need) {
  while (__hip_atomic_load(f, __ATOMIC_RELAXED, __HIP_MEMORY_SCOPE_AGENT) < need)
    __builtin_amdgcn_s_sleep(1);
}
// LDS flag ops (workgroup scope: ds ops + waitcnt, ~60 cyc round trip)
__device__ __forceinline__ void lspin_ge(int* p, int need) {
  while (__hip_atomic_load(p, __ATOMIC_ACQUIRE, __HIP_MEMORY_SCOPE_WORKGROUP) < need)
    __builtin_amdgcn_s_sleep(0);
  __builtin_amdgcn_sched_barrier(0);
}
__device__ __forceinline__ void lset(int* p, int v) {
  __hip_atomic_store(p, v, __ATOMIC_RELEASE, __HIP_MEMORY_SCOPE_WORKGROUP);
}
__device__ __forceinline__ void cvt8(const f32x4& p, const f32x4& q, s16x8& bh, s16x8& bl) {
  const float pv[8] = {p.x, p.y, p.z, p.w, q.x, q.y, q.z, q.w};
#pragma unroll
  for (int j = 0; j < 8; ++j) {
    const short h = f2bf(pv[j]);
    bh[j] = h;
    bl[j] = f2bf(pv[j] - bf2f(h));
  }
}

#define GLLP(g, l) __builtin_amdgcn_global_load_lds(                          \
    (const __attribute__((address_space(1))) void*)(g),                       \
    (__attribute__((address_space(3))) void*)(l), 16, 0, 0)
#define GLLC(g, l) __builtin_amdgcn_global_load_lds(                          \
    (const __attribute__((address_space(1))) void*)(g),                       \
    (__attribute__((address_space(3))) void*)(l), 16, 0, 0x11)

#define VMCNT4() do { asm volatile("s_waitcnt vmcnt(4)" ::: "memory"); __builtin_amdgcn_sched_barrier(0); } while (0)
#define VMCNT0() do { asm volatile("s_waitcnt vmcnt(0)" ::: "memory"); __builtin_amdgcn_sched_barrier(0); } while (0)
#define LGKM0()  do { asm volatile("s_waitcnt lgkmcnt(0)" ::: "memory"); __builtin_amdgcn_sched_barrier(0); } while (0)

__global__ __launch_bounds__(256)
void lstm_persist(
    const float* __restrict__ x,
    const float* __restrict__ Wih0, const float* __restrict__ Whh0,
    const float* __restrict__ bih0, const float* __restrict__ bhh0,
    const float* __restrict__ Wih1, const float* __restrict__ Whh1,
    const float* __restrict__ bih1, const float* __restrict__ bhh1,
    const float* __restrict__ h0c, const float* __restrict__ c0c,
    float* __restrict__ out,
    short* __restrict__ r0hi, short* __restrict__ r0lo,
    short* __restrict__ r1hi, short* __restrict__ r1lo,
    int* __restrict__ flags0, int* __restrict__ flags1)
{
  __shared__ __align__(16) char LDS[158048];
  char* Whi = LDS;                       // 16 rows x 2048 B, swizzled (k<<1)^((row&15)<<4)
  char* Wlo = LDS + O_WLO;
  char* Ast = LDS + O_AST;
  char* const Bst0 = LDS + O_B0;
  char* const Bst1 = LDS + O_B1;
  float* gbufF = (float*)(LDS + O_GB);
  int* lf = (int*)(LDS + O_LF);          // 0,1=as(stage done) 2,3=am(reads done) 4,5=xf 6,7=xc

  const int tid   = (int)threadIdx.x;
  const int lane  = tid & 63;
  const int w     = tid >> 6;            // 0,1 = A (recurrent+cell); 2,3 = B (xg producer)
  const int layer = (int)(blockIdx.x >> 7);
  const int lb    = (int)(blockIdx.x & (NBLK - 1));
  const int j0    = lb << 2;
  const bool isA  = (w < 2);

  const float* Wih = layer ? Wih1 : Wih0;
  const float* Whh = layer ? Whh1 : Whh0;
  const float* bih = layer ? bih1 : bih0;
  const float* bhh = layer ? bhh1 : bhh0;
  short* rhiO = layer ? r1hi : r0hi;     // own-layer h ring
  short* rloO = layer ? r1lo : r0lo;
  int* flO = layer ? flags1 : flags0;    // 256 flags/layer (2 per block)
  const int rmask = layer ? (RING1 - 1) : (RING0 - 1);

  // ---- prologue: W -> bf16 hi/lo planes (src-swizzled) ----
  for (int idx = tid; idx < 16 * 1024; idx += 256) {
    const int row = idx >> 10;
    const int k   = idx & 1023;          // 0-511 Wih, 512-1023 Whh
    const int rg  = ((row >> 2) << 9) + j0 + (row & 3);
    const float v = (k < 512) ? Wih[(rg << 9) + k] : Whh[(rg << 9) + (k - 512)];
    const short h = f2bf(v);
    const short l = f2bf(v - bf2f(h));
    const int byte = (row << 11) + ((k << 1) ^ ((row & 15) << 4));
    *(short*)(Whi + byte) = h;
    *(short*)(Wlo + byte) = l;
  }
  float creg = 0.0f;
  float bias_[4] = {0.f, 0.f, 0.f, 0.f};
  int jjC = 0, bC = 0;
  if (isA) {
    jjC = lane >> 4;
    bC  = (w << 4) + (lane & 15);
    creg = c0c[layer * 512 + j0 + jjC];
#pragma unroll
    for (int g = 0; g < 4; ++g) {
      const int rg = (g << 9) + j0 + jjC;
      bias_[g] = bih[rg] + bhh[rg];
    }
  }

  // MFMA lane constants
  const int arow = lane & 15;
  const int kg   = lane >> 4;
  const int wsz  = arow << 4;
  const int bbA  = (w << 4) + (lane & 15);
  const int uszA = (bbA & 15) << 4;
  const int bbB  = ((w - 2) << 4) + (lane & 15);
  const int uszB  = (bbB & 15) << 4;
  const int uszB7 = (bbB & 7) << 4;

  // ---- prologue: stage A(0) = fp32 broadcast of h init ----
  if (isA) {
    const char* src0 = (const char*)(h0c + layer * 512);
#pragma unroll 1
    for (int i = 0; i < 32; ++i) {
      const int g = (w << 5) + i;
      const int b = g >> 1, half = g & 1;
      GLLP(src0 + (half << 10) + ((lane << 4) ^ ((b & 15) << 4)),
           Ast + (b << 11) + (half << 10));
    }
    VMCNT0();
  }
  if (tid == 0) {
    lf[0] = 1; lf[1] = 1;                // prologue staging counts as stage #1
    lf[2] = 0; lf[3] = 0; lf[4] = 0; lf[5] = 0; lf[6] = 0; lf[7] = 0;
  }
  LGKM0();
  __builtin_amdgcn_s_barrier();          // the ONLY barrier; none in the main loops
  __builtin_amdgcn_sched_barrier(0);

  if (isA) {
    // ================= A: recurrent chain =================
#pragma unroll 1
    for (int s = 0; s < TT; ++s) {
      lspin_ge(&lf[0], s + 1);           // both planes staged
      lspin_ge(&lf[1], s + 1);
      f32x4 a0 = {0.f,0.f,0.f,0.f}, a1 = {0.f,0.f,0.f,0.f};
#pragma unroll
      for (int ks = 0; ks < 16; ++ks) {
        const int wk = 512 + (ks << 5) + (kg << 3);
        const int wb = ((wk << 1) ^ wsz);
        const s16x8 ah = *(const s16x8*)(Whi + (arow << 11) + wb);
        const s16x8 al = *(const s16x8*)(Wlo + (arow << 11) + wb);
        const int uk = (ks << 5) + (kg << 3);
        s16x8 bh, bl;
        if (s == 0) {
          const f32x4 p = *(const f32x4*)(Ast + (bbA << 11) + ((uk << 2) ^ uszA));
          const f32x4 q = *(const f32x4*)(Ast + (bbA << 11) + (((uk + 4) << 2) ^ uszA));
          cvt8(p, q, bh, bl);
        } else {
          const int ub = (uk << 1) ^ uszA;
          bh = *(const s16x8*)(Ast + (bbA << 10) + ub);
          bl = *(const s16x8*)(Ast + 32768 + (bbA << 10) + ub);
        }
        if (ks & 1) {
          a1 = __builtin_amdgcn_mfma_f32_16x16x32_bf16(ah, bh, a1, 0, 0, 0);
          a1 = __builtin_amdgcn_mfma_f32_16x16x32_bf16(ah, bl, a1, 0, 0, 0);
          a1 = __builtin_amdgcn_mfma_f32_16x16x32_bf16(al, bh, a1, 0, 0, 0);
        } else {
          a0 = __builtin_amdgcn_mfma_f32_16x16x32_bf16(ah, bh, a0, 0, 0, 0);
          a0 = __builtin_amdgcn_mfma_f32_16x16x32_bf16(ah, bl, a0, 0, 0, 0);
          a0 = __builtin_amdgcn_mfma_f32_16x16x32_bf16(al, bh, a0, 0, 0, 0);
        }
      }
      const f32x4 c = a0 + a1;
#pragma unroll
      for (int r = 0; r < 4; ++r) gbufF[((kg << 2) + r) * 33 + bbA] = c[r];
      LGKM0();
      lset(&lf[2 + w], s + 1);           // plane reads for step s done
      lspin_ge(&lf[4 + w], s + 1);       // xg[s] ready from B pair
      if (layer == 0 && s >= RING0) {    // r0 slot reuse: L1 consumed y0[s-8]
        poll_ge(flags1 + tid, s - RING0 + 1);
        poll_ge(flags1 + 128 + tid, s - RING0 + 1);
      }
      // ---- cell (all 128 A-lanes) ----
      const float* xg = (const float*)(LDS + O_XGB) + (s & 3) * 528;
      float gv[4];
#pragma unroll
      for (int g = 0; g < 4; ++g) {
        const int rowi = ((g << 2) + jjC) * 33 + bC;
        gv[g] = gbufF[rowi] + xg[rowi] + bias_[g];
      }
      const float cn = sigf(gv[1]) * creg + sigf(gv[0]) * tanh_(gv[2]);
      const float hn = sigf(gv[3]) * tanh_(cn);
      creg = cn;
      const int j = j0 + jjC;
      const int slot = s & rmask;
      const short hb = f2bf(hn);
      const short lo2 = f2bf(hn - bf2f(hb));
      st_short_coh(rhiO + (((slot << 5) + bC) << 9) + j, (int)hb);
      st_short_coh(rloO + (((slot << 5) + bC) << 9) + j, (int)lo2);
      if (layer == 1) out[(((size_t)bC * 2048 + s) << 9) + j] = hn;
      if (s == TT - 1) out[HFO + (size_t)(((layer << 5) + bC) << 9) + j] = hn;
      VMCNT0();                          // h planes at coherence point
      if (lane == 0) st_flag(flO + (lb << 1) + w, s + 1);
      lset(&lf[6 + w], s + 1);           // xg slot consumed
      if (s + 1 < TT) {
        poll_ge(flO + tid, s + 1);       // all blocks' h[s] complete
        poll_ge(flO + 128 + tid, s + 1);
        lspin_ge(&lf[2 + (1 - w)], s + 1);  // other wave done reading plane w
        const char* sp = (w == 0) ? (const char*)rhiO : (const char*)rloO;
#pragma unroll 1
        for (int b = 0; b < 32; ++b) {
          GLLC(sp + ((((slot << 5) + b) << 10)) + ((lane << 4) ^ ((b & 15) << 4)),
               Ast + (w << 15) + (b << 10));
        }
        VMCNT0();
        lset(&lf[w], s + 2);             // plane w staged for step s+1
      }
    }
    out[CFO + (size_t)(((layer << 5) + bC) << 9) + j0 + jjC] = creg;
  } else {
    // ================= B: xg producer (runs ahead, LDS-gated) =================
    const int v = w - 2;
    auto issueChunk = [&](char* buf, int c, int t) {
      if (layer == 0) {                  // x[.,t,c*64..]: 16 rows x 256 B per wave
#pragma unroll
        for (int j = 0; j < 4; ++j) {
          const int b = (v << 4) + (j << 2) + (lane >> 4);
          const char* src = (const char*)x
              + ((((size_t)b * 2048 + t) * 512 + ((size_t)c << 6)) << 2)
              + (((lane & 15) << 4) ^ ((b & 15) << 4));
          GLLP(src, buf + (((v << 4) + (j << 2)) << 8));
        }
      } else {                           // y0[t] planes from r0 ring (8 slots)
#pragma unroll
        for (int j = 0; j < 4; ++j) {
          const int hi = (j < 2);
          const int b = (v << 4) + ((j & 1) << 3) + (lane >> 3);
          const char* rb = hi ? (const char*)r0hi : (const char*)r0lo;
          const char* src = rb
              + ((((size_t)(t & 7) * 32 + b) * 512 + ((size_t)c << 6)) << 1)
              + (((lane & 7) << 4) ^ ((b & 7) << 4));
          GLLC(src, buf + (hi ? 0 : 4096) + (((v << 4) + ((j & 1) << 3)) << 7));
        }
      }
    };
#pragma unroll 1
    for (int t = 0; t < TT; ++t) {
      if (layer == 1) {                  // y0[t] available
        poll_ge(flags0 + (tid & 127), t + 1);
        poll_ge(flags0 + (tid & 127) + 128, t + 1);
      }
      lspin_ge(&lf[6 + v], t - 3);       // xg ring slot t&3 free
      f32x4 a0 = {0.f,0.f,0.f,0.f}, a1 = {0.f,0.f,0.f,0.f};
      issueChunk(Bst0, 0, t);
      issueChunk(Bst1, 1, t);
#pragma unroll 1
      for (int c = 0; c < 8; ++c) {
        if (c == 7) { VMCNT0(); } else { VMCNT4(); }
        char* buf = (c & 1) ? Bst1 : Bst0;
#pragma unroll
        for (int i = 0; i < 2; ++i) {
          const int wk = (c << 6) + (i << 5) + (kg << 3);
          const int wb = ((wk << 1) ^ wsz);
          const s16x8 ah = *(const s16x8*)(Whi + (arow << 11) + wb);
          const s16x8 al = *(const s16x8*)(Wlo + (arow << 11) + wb);
          const int kk = (i << 5) + (kg << 3);
          s16x8 bh, bl;
          if (layer == 0) {
            const f32x4 p = *(const f32x4*)(buf + (bbB << 8) + ((kk << 2) ^ uszB));
            const f32x4 q = *(const f32x4*)(buf + (bbB << 8) + (((kk + 4) << 2) ^ uszB));
            cvt8(p, q, bh, bl);
          } else {
            const int ub = (kk << 1) ^ uszB7;
            bh = *(const s16x8*)(buf + (bbB << 7) + ub);
            bl = *(const s16x8*)(buf + 4096 + (bbB << 7) + ub);
          }
          if (i & 1) {
            a1 = __builtin_amdgcn_mfma_f32_16x16x32_bf16(ah, bh, a1, 0, 0, 0);
            a1 = __builtin_amdgcn_mfma_f32_16x16x32_bf16(ah, bl, a1, 0, 0, 0);
            a1 = __builtin_amdgcn_mfma_f32_16x16x32_bf16(al, bh, a1, 0, 0, 0);
          } else {
            a0 = __builtin_amdgcn_mfma_f32_16x16x32_bf16(ah, bh, a0, 0, 0, 0);
            a0 = __builtin_amdgcn_mfma_f32_16x16x32_bf16(ah, bl, a0, 0, 0, 0);
            a0 = __builtin_amdgcn_mfma_f32_16x16x32_bf16(al, bh, a0, 0, 0, 0);
          }
        }
        __builtin_amdgcn_sched_barrier(0);  // reads of buf precede re-issue into it
        if (c < 6) issueChunk(buf, c + 2, t);
      }
      float* xg = (float*)(LDS + O_XGB) + (t & 3) * 528;
      const f32x4 cf = a0 + a1;
#pragma unroll
      for (int r = 0; r < 4; ++r) xg[((kg << 2) + r) * 33 + bbB] = cf[r];
      lset(&lf[4 + v], t + 1);           // xg[t] published (release orders ds writes)
    }
  }
}

extern "C" void kernel_launch(void* const* d_in, const int* in_sizes, int n_in,
                              void* d_out, int out_size, void* d_ws, size_t ws_size,
                              hipStream_t stream) {
  (void)in_sizes; (void)n_in; (void)out_size; (void)ws_size;
  const float* x    = (const float*)d_in[0];
  const float* Wih0 = (const float*)d_in[1];
  const float* Whh0 = (const float*)d_in[2];
  const float* bih0 = (const float*)d_in[3];
  const float* bhh0 = (const float*)d_in[4];
  const float* Wih1 = (const float*)d_in[5];
  const float* Whh1 = (const float*)d_in[6];
  const float* bih1 = (const float*)d_in[7];
  const float* bhh1 = (const float*)d_in[8];
  const float* h0   = (const float*)d_in[9];
  const float* c0   = (const float*)d_in[10];

  float* out = (float*)d_out;
  short* r0hi = (short*)d_ws;                            // 8 slots x 32 x 512 x 2B = 256 KB
  short* r0lo = (short*)((char*)d_ws + (256 << 10));     // 256 KB
  short* r1hi = (short*)((char*)d_ws + (512 << 10));     // 4 slots = 128 KB
  short* r1lo = (short*)((char*)d_ws + (640 << 10));     // 128 KB
  int* flags0 = (int*)((char*)d_ws + (768 << 10));       // 256 ints
  int* flags1 = (int*)((char*)d_ws + (768 << 10) + 1024);

  hipMemsetAsync(flags0, 0, 2048, stream);

  hipLaunchKernelGGL(lstm_persist, dim3(2 * NBLK), dim3(256), 0, stream,
                     x, Wih0, Whh0, bih0, bhh0, Wih1, Whh1, bih1, bhh1,
                     h0, c0, out, r0hi, r0lo, r1hi, r1lo, flags0, flags1);
}

// Round 14
// 19215.739 us; speedup vs baseline: 1.2769x; 1.0359x over previous
//
#include <hip/hip_runtime.h>

namespace {
constexpr int TT  = 2048;
constexpr int NBL = 64;                 // blocks per layer
constexpr size_t YSZ = (size_t)32 * TT * 512;
constexpr size_t HFO = YSZ;
constexpr size_t CFO = YSZ + (size_t)2 * 32 * 512;
// LDS map (157760 B)
constexpr int O_WLO  = 65536;           // W lo plane (hi at 0); 32 rows x 2048 B each
constexpr int O_GA   = 131072;          // 8 tiles x 272 floats = 8704 B
constexpr int O_XGB  = 139776;          // 2 slots x 8704 B
constexpr int O_HOUT = 157184;          // 32 x 8 shorts = 512 B
constexpr int O_LF   = 157696;          // 16 ints: ga[4] xf[4] xcw[4] pad[4]
constexpr int TILE_F = 272;             // 16 rows x 17 floats
constexpr int LF_GA = 0, LF_XF = 4, LF_XC = 8;
}

typedef float f32x4 __attribute__((ext_vector_type(4)));
typedef short s16x8 __attribute__((ext_vector_type(8)));

__device__ __forceinline__ float sigf(float v)  { return 1.0f / (1.0f + __expf(-v)); }
__device__ __forceinline__ float tanh_(float v) { return 1.0f - 2.0f / (__expf(2.0f * v) + 1.0f); }
__device__ __forceinline__ short f2bf(float v) {
  unsigned u = __float_as_uint(v);
  u += 0x7FFFu + ((u >> 16) & 1u);
  return (short)(u >> 16);
}
__device__ __forceinline__ float bf2f(short h) {
  return __uint_as_float(((unsigned)(unsigned short)h) << 16);
}
__device__ __forceinline__ s16x8 cvt8hi(const f32x4& p, const f32x4& q) {
  s16x8 r;
  r[0] = f2bf(p.x); r[1] = f2bf(p.y); r[2] = f2bf(p.z); r[3] = f2bf(p.w);
  r[4] = f2bf(q.x); r[5] = f2bf(q.y); r[6] = f2bf(q.z); r[7] = f2bf(q.w);
  return r;
}
// coherent 16B load/store (sc1: bypass L1/L2 -> shared coherence point)
__device__ __forceinline__ s16x8 ld_bf8_coh(const void* p) {
  s16x8 r;
  asm volatile("global_load_dwordx4 %0, %1, off sc1" : "=v"(r) : "v"(p) : "memory");
  return r;
}
__device__ __forceinline__ void st_b16_coh(void* p, s16x8 v) {
  asm volatile("global_store_dwordx4 %0, %1, off sc1" :: "v"(p), "v"(v) : "memory");
}
__device__ __forceinline__ void st_flag(int* p, int v) {
  __hip_atomic_store(p, v, __ATOMIC_RELAXED, __HIP_MEMORY_SCOPE_AGENT);
}
__device__ __forceinline__ void poll_ge(const int* f, int need) {
  while (__hip_atomic_load(f, __ATOMIC_RELAXED, __HIP_MEMORY_SCOPE_AGENT) < need)
    __builtin_amdgcn_s_sleep(1);
}
__device__ __forceinline__ void lspin_ge(int* p, int need) {
  while (__hip_atomic_load(p, __ATOMIC_ACQUIRE, __HIP_MEMORY_SCOPE_WORKGROUP) < need)
    __builtin_amdgcn_s_sleep(0);
  __builtin_amdgcn_sched_barrier(0);
}
__device__ __forceinline__ void lset(int* p, int v) {
  __hip_atomic_store(p, v, __ATOMIC_RELEASE, __HIP_MEMORY_SCOPE_WORKGROUP);
}

#define VMCNT0() do { asm volatile("s_waitcnt vmcnt(0)" ::: "memory"); __builtin_amdgcn_sched_barrier(0); } while (0)
#define LGKM0()  do { asm volatile("s_waitcnt lgkmcnt(0)" ::: "memory"); __builtin_amdgcn_sched_barrier(0); } while (0)

#define MFMA __builtin_amdgcn_mfma_f32_16x16x32_bf16

__global__ __launch_bounds__(512)
void lstm_persist(
    const float* __restrict__ x,
    const float* __restrict__ Wih0, const float* __restrict__ Whh0,
    const float* __restrict__ bih0, const float* __restrict__ bhh0,
    const float* __restrict__ Wih1, const float* __restrict__ Whh1,
    const float* __restrict__ bih1, const float* __restrict__ bhh1,
    const float* __restrict__ h0c, const float* __restrict__ c0c,
    float* __restrict__ out,
    short* __restrict__ r0hi, short* __restrict__ r1hi,
    int* __restrict__ flags0, int* __restrict__ flags1)
{
  __shared__ __align__(16) char LDS[157760];
  char* Whi = LDS;                       // swizzled: (row<<11) + ((k<<1) ^ ((row&15)<<4))
  char* Wlo = LDS + O_WLO;
  float* gAp = (float*)(LDS + O_GA);
  float* xgp = (float*)(LDS + O_XGB);
  int* lf = (int*)(LDS + O_LF);

  const int tid   = (int)threadIdx.x;
  const int lane  = tid & 63;
  const int w     = tid >> 6;            // 0-3: A (recurrent + cell); 4-7: B (ff producer)
  const int layer = (int)(blockIdx.x >> 6);
  const int lb    = (int)(blockIdx.x & (NBL - 1));
  const int j0    = lb << 3;             // 8 columns per block
  const bool isA  = (w < 4);

  const float* Wih = layer ? Wih1 : Wih0;
  const float* Whh = layer ? Whh1 : Whh0;
  const float* bih = layer ? bih1 : bih0;
  const float* bhh = layer ? bhh1 : bhh0;
  short* rhiO = layer ? r1hi : r0hi;     // own-layer h-hi plane ring
  int* flO = layer ? flags1 : flags0;    // 64 flags/layer; value v => h(v-2) stored
  const int rmask = layer ? 3 : 7;       // ring slots: L0=8 (feeds L1-B), L1=4

  // ---- prologue: W' -> bf16 hi/lo LDS planes (32 rows x 1024 cols) ----
  for (int idx = tid; idx < 32 * 1024; idx += 512) {
    const int row = idx >> 10;           // g*8 + jj
    const int k   = idx & 1023;          // 0-511: Wih, 512-1023: Whh
    const int rg  = ((row >> 3) << 9) + j0 + (row & 7);
    const float vv = (k < 512) ? Wih[(rg << 9) + k] : Whh[(rg << 9) + (k - 512)];
    const short h = f2bf(vv);
    const short l = f2bf(vv - bf2f(h));
    const int byte = (row << 11) + ((k << 1) ^ ((row & 15) << 4));
    *(short*)(Whi + byte) = h;
    *(short*)(Wlo + byte) = l;
  }
  // ---- prologue: stage h(-1) = h0c[layer] into ring slot rmask (all blocks write
  // identical values -> benign race), as bf16-hi ----
  for (int i = tid; i < 2048; i += 512) {
    const int b = i >> 6, c8 = i & 63;
    const float* hp = h0c + layer * 512 + (c8 << 3);
    const f32x4 p = *(const f32x4*)hp;
    const f32x4 q = *(const f32x4*)(hp + 4);
    st_b16_coh((char*)rhiO + (rmask << 15) + (b << 10) + (c8 << 4), cvt8hi(p, q));
  }
  VMCNT0();
  if (tid == 0) {
    st_flag(flO + lb, 1);                // "h(-1) stored"
#pragma unroll
    for (int i = 0; i < 16; ++i) lf[i] = 0;
  }
  float creg = 0.0f;
  float bias_[4] = {0.f, 0.f, 0.f, 0.f};
  int jjC = 0, bC = 0;
  if (isA) {                             // 256 A-threads = 256 cells (8 cols x 32 b)
    jjC = tid >> 5;                      // 0..7
    bC  = tid & 31;
    creg = c0c[layer * 512 + j0 + jjC];
#pragma unroll
    for (int g = 0; g < 4; ++g) bias_[g] = bih[(g << 9) + j0 + jjC] + bhh[(g << 9) + j0 + jjC];
  }
  LGKM0();
  __builtin_amdgcn_s_barrier();          // only barrier (W + lf ready)
  __builtin_amdgcn_sched_barrier(0);

  // MFMA lane constants: wave owns (batch-group bg, K-quarter kh), both 16-row groups
  const int kg = lane >> 4;

  if (isA) {
    // ================= A: recurrent half (W cols 512+), cell =================
    const int bg = w & 1, kh = w >> 1;
    const int b_ld = (bg << 4) + (lane & 15);
    const int colb = (kh << 8) + (kg << 3);
#pragma unroll 1
    for (int s = 0; s < TT; ++s) {
      poll_ge(flO + lane, s + 1);        // all 64 blocks stored h(s-1)
      const int rslot = (s + rmask) & rmask;
      s16x8 bh[8];
      const char* pb = (const char*)rhiO + (rslot << 15) + (b_ld << 10) + (colb << 1);
#pragma unroll
      for (int ks = 0; ks < 8; ++ks) bh[ks] = ld_bf8_coh(pb + (ks << 6));
      VMCNT0();
      f32x4 acc[2][2];
#pragma unroll
      for (int rg = 0; rg < 2; ++rg)
#pragma unroll
        for (int p = 0; p < 2; ++p) acc[rg][p] = (f32x4){0.f, 0.f, 0.f, 0.f};
#pragma unroll
      for (int ks = 0; ks < 8; ++ks)
#pragma unroll
        for (int rg = 0; rg < 2; ++rg) {
          const int wrow = (rg << 4) + (lane & 15);
          const int wk = 512 + (kh << 8) + (ks << 5) + (kg << 3);
          const int wb = (wrow << 11) + ((wk << 1) ^ ((wrow & 15) << 4));
          acc[rg][ks & 1] = MFMA(*(const s16x8*)(Whi + wb), bh[ks], acc[rg][ks & 1], 0, 0, 0);
          acc[rg][ks & 1] = MFMA(*(const s16x8*)(Wlo + wb), bh[ks], acc[rg][ks & 1], 0, 0, 0);
        }
#pragma unroll
      for (int rg = 0; rg < 2; ++rg) {
        const f32x4 c = acc[rg][0] + acc[rg][1];
        float* tp = gAp + ((kh << 2) + (rg << 1) + bg) * TILE_F + (kg << 2) * 17 + (lane & 15);
#pragma unroll
        for (int r = 0; r < 4; ++r) tp[r * 17] = c[r];
      }
      LGKM0();
      lset(&lf[LF_GA + w], s + 1);
#pragma unroll
      for (int i = 0; i < 4; ++i) lspin_ge(&lf[LF_GA + i], s + 1);
#pragma unroll
      for (int i = 0; i < 4; ++i) lspin_ge(&lf[LF_XF + i], s + 1);
      // ---- cell ----
      const float* xgs = xgp + (s & 1) * 2176;
      float gv[4];
#pragma unroll
      for (int g = 0; g < 4; ++g) {
        const int row = (g << 3) + jjC;
        const int base = (((row >> 4) << 1) + (bC >> 4)) * TILE_F + (row & 15) * 17 + (bC & 15);
        gv[g] = gAp[base] + gAp[base + 4 * TILE_F] + xgs[base] + xgs[base + 4 * TILE_F] + bias_[g];
      }
      const float cn = sigf(gv[1]) * creg + sigf(gv[0]) * tanh_(gv[2]);
      const float hn = sigf(gv[3]) * tanh_(cn);
      creg = cn;
      if (layer == 1) out[((size_t)((bC << 11) + s) << 9) + j0 + jjC] = hn;
      if (s == TT - 1) out[HFO + (size_t)(((layer << 5) + bC) << 9) + j0 + jjC] = hn;
      *(short*)(LDS + O_HOUT + (bC << 4) + (jjC << 1)) = f2bf(hn);
      LGKM0();
      lset(&lf[LF_XC + w], s + 1);       // cell done (hout written, xg consumed)
      if (w == 0) {
        lspin_ge(&lf[LF_XC + 1], s + 1);
        lspin_ge(&lf[LF_XC + 2], s + 1);
        lspin_ge(&lf[LF_XC + 3], s + 1);
        if (layer == 0 && s >= 8) poll_ge(flags1 + lane, s - 6);  // L1 past y0(s-8)
        if (lane < 32) {
          const s16x8 hv = *(const s16x8*)(LDS + O_HOUT + (lane << 4));
          st_b16_coh((char*)rhiO + ((s & rmask) << 15) + (lane << 10) + (j0 << 1), hv);
        }
        VMCNT0();
        if (lane == 0) st_flag(flO + lb, s + 2);
      }
    }
    out[CFO + (size_t)(((layer << 5) + bC) << 9) + j0 + jjC] = creg;
  } else {
    // ================= B: feed-forward half (W cols 0-511), runs ahead =================
    const int v = w - 4;
    const int bg = v & 1, kh = v >> 1;
    const int b_ld = (bg << 4) + (lane & 15);
    const int colb = (kh << 8) + (kg << 3);
#pragma unroll 1
    for (int t = 0; t < TT; ++t) {
#pragma unroll
      for (int i = 0; i < 4; ++i) lspin_ge(&lf[LF_XC + i], t - 1);  // xg slot t&1 free
      f32x4 acc[2][2];
#pragma unroll
      for (int rg = 0; rg < 2; ++rg)
#pragma unroll
        for (int p = 0; p < 2; ++p) acc[rg][p] = (f32x4){0.f, 0.f, 0.f, 0.f};
      if (layer == 0) {
        // x[t] fp32 via L2-cacheable loads, cvt to bf16-hi in-register
#pragma unroll 1
        for (int round = 0; round < 2; ++round) {
          f32x4 xr[8];
#pragma unroll
          for (int i = 0; i < 8; ++i) {
            const int ks = (round << 2) + (i >> 1);
            const int col = colb + (ks << 5) + ((i & 1) << 2);
            xr[i] = *(const f32x4*)(x + ((size_t)((b_ld << 11) + t) << 9) + col);
          }
#pragma unroll
          for (int sl = 0; sl < 4; ++sl) {
            const int ks = (round << 2) + sl;
            const s16x8 bh = cvt8hi(xr[sl << 1], xr[(sl << 1) + 1]);
#pragma unroll
            for (int rg = 0; rg < 2; ++rg) {
              const int wrow = (rg << 4) + (lane & 15);
              const int wk = (kh << 8) + (ks << 5) + (kg << 3);
              const int wb = (wrow << 11) + ((wk << 1) ^ ((wrow & 15) << 4));
              acc[rg][ks & 1] = MFMA(*(const s16x8*)(Whi + wb), bh, acc[rg][ks & 1], 0, 0, 0);
              acc[rg][ks & 1] = MFMA(*(const s16x8*)(Wlo + wb), bh, acc[rg][ks & 1], 0, 0, 0);
            }
          }
        }
      } else {
        poll_ge(flags0 + lane, t + 2);   // y0(t) = h0(t) stored by all L0 blocks
        s16x8 bh[8];
        const char* pb = (const char*)r0hi + ((t & 7) << 15) + (b_ld << 10) + (colb << 1);
#pragma unroll
        for (int ks = 0; ks < 8; ++ks) bh[ks] = ld_bf8_coh(pb + (ks << 6));
        VMCNT0();
#pragma unroll
        for (int ks = 0; ks < 8; ++ks)
#pragma unroll
          for (int rg = 0; rg < 2; ++rg) {
            const int wrow = (rg << 4) + (lane & 15);
            const int wk = (kh << 8) + (ks << 5) + (kg << 3);
            const int wb = (wrow << 11) + ((wk << 1) ^ ((wrow & 15) << 4));
            acc[rg][ks & 1] = MFMA(*(const s16x8*)(Whi + wb), bh[ks], acc[rg][ks & 1], 0, 0, 0);
            acc[rg][ks & 1] = MFMA(*(const s16x8*)(Wlo + wb), bh[ks], acc[rg][ks & 1], 0, 0, 0);
          }
      }
      float* xps = xgp + (t & 1) * 2176;
#pragma unroll
      for (int rg = 0; rg < 2; ++rg) {
        const f32x4 c = acc[rg][0] + acc[rg][1];
        float* tp = xps + ((kh << 2) + (rg << 1) + bg) * TILE_F + (kg << 2) * 17 + (lane & 15);
#pragma unroll
        for (int r = 0; r < 4; ++r) tp[r * 17] = c[r];
      }
      LGKM0();
      lset(&lf[LF_XF + v], t + 1);       // xg(t) published
    }
  }
}

extern "C" void kernel_launch(void* const* d_in, const int* in_sizes, int n_in,
                              void* d_out, int out_size, void* d_ws, size_t ws_size,
                              hipStream_t stream) {
  (void)in_sizes; (void)n_in; (void)out_size; (void)ws_size;
  const float* x    = (const float*)d_in[0];
  const float* Wih0 = (const float*)d_in[1];
  const float* Whh0 = (const float*)d_in[2];
  const float* bih0 = (const float*)d_in[3];
  const float* bhh0 = (const float*)d_in[4];
  const float* Wih1 = (const float*)d_in[5];
  const float* Whh1 = (const float*)d_in[6];
  const float* bih1 = (const float*)d_in[7];
  const float* bhh1 = (const float*)d_in[8];
  const float* h0   = (const float*)d_in[9];
  const float* c0   = (const float*)d_in[10];

  float* out = (float*)d_out;
  short* r0hi = (short*)d_ws;                            // 8 slots x 32 KB = 256 KB
  short* r1hi = (short*)((char*)d_ws + (256 << 10));     // 4 slots x 32 KB = 128 KB
  int* flags0 = (int*)((char*)d_ws + (384 << 10));       // 64 ints
  int* flags1 = (int*)((char*)d_ws + (384 << 10) + 256); // 64 ints

  hipMemsetAsync(flags0, 0, 512, stream);

  hipLaunchKernelGGL(lstm_persist, dim3(2 * NBL), dim3(512), 0, stream,
                     x, Wih0, Whh0, bih0, bhh0, Wih1, Whh1, bih1, bhh1,
                     h0, c0, out, r0hi, r1hi, flags0, flags1);
}